// Round 1
// baseline (3162.924 us; speedup 1.0000x reference)
//
#include <hip/hip_runtime.h>
#include <cmath>

// EMD approxmatch, B=16, N=M=2048, f32.
// State in d_ws: satl[B*N], satr[B*M], ratioL[B*N], ratioR[B*M], costAcc[1].
// Per level: col_pass (ratioR + satr update), row_finish (cost + satl update,
// fused with next level's row-sum -> ratioL). row_start seeds level 0.

#define NB 16
#define NN 2048
#define NM 2048
#define EPS_F 1e-9f

__global__ __launch_bounds__(256) void init_state(float* __restrict__ satl,
                                                  float* __restrict__ satr,
                                                  float* __restrict__ costAcc) {
    int i = blockIdx.x * 256 + threadIdx.x;
    if (i < NB * NN) satl[i] = 1.0f;   // factorl = max(N,M)//N = 1
    if (i < NB * NM) satr[i] = 1.0f;   // factorr = 1
    if (i == 0) costAcc[0] = 0.0f;
}

// ratioL[n] = satl[n] / (sum_m exp(level*d2)*satr[m] + eps)
__global__ __launch_bounds__(256) void row_start(const float* __restrict__ pred,
                                                 const float* __restrict__ gt,
                                                 const float* __restrict__ satl,
                                                 const float* __restrict__ satr,
                                                 float* __restrict__ ratioL,
                                                 float level) {
    __shared__ float sx[NM], sy[NM], sz[NM], sr[NM];
    const int b = blockIdx.x >> 8;              // 256 blocks per batch (8 rows each)
    const int rbase = (blockIdx.x & 255) * 8;
    const float* gtb = gt + (size_t)b * NM * 3;
    for (int i = threadIdx.x; i < NM; i += 256) {
        sx[i] = gtb[i * 3 + 0];
        sy[i] = gtb[i * 3 + 1];
        sz[i] = gtb[i * 3 + 2];
        sr[i] = satr[b * NM + i];
    }
    __syncthreads();
    const int wave = threadIdx.x >> 6, lane = threadIdx.x & 63;
    for (int r = 0; r < 2; ++r) {
        const int row = rbase + wave * 2 + r;
        const float px = pred[((size_t)b * NN + row) * 3 + 0];
        const float py = pred[((size_t)b * NN + row) * 3 + 1];
        const float pz = pred[((size_t)b * NN + row) * 3 + 2];
        float acc = 0.0f;
        #pragma unroll 4
        for (int i = lane; i < NM; i += 64) {
            float dx = px - sx[i], dy = py - sy[i], dz = pz - sz[i];
            float d2 = dx * dx + dy * dy + dz * dz;
            acc += expf(level * d2) * sr[i];
        }
        #pragma unroll
        for (int o = 1; o < 64; o <<= 1) acc += __shfl_xor(acc, o);
        if (lane == 0) {
            int idx = b * NN + row;
            ratioL[idx] = satl[idx] / (acc + EPS_F);
        }
    }
}

// sumr[m] = sum_n exp(level*d2)*ratioL[n];
// ratioR[m] = satr*min(satr/(satr*sumr+eps),1); satr -= ratioR*sumr (clamped)
__global__ __launch_bounds__(256) void col_pass(const float* __restrict__ pred,
                                                const float* __restrict__ gt,
                                                const float* __restrict__ ratioL,
                                                float* __restrict__ ratioR,
                                                float* __restrict__ satr,
                                                float level) {
    __shared__ float sx[NN], sy[NN], sz[NN], sl[NN];
    const int b = blockIdx.x >> 8;
    const int cbase = (blockIdx.x & 255) * 8;
    const float* pb = pred + (size_t)b * NN * 3;
    for (int i = threadIdx.x; i < NN; i += 256) {
        sx[i] = pb[i * 3 + 0];
        sy[i] = pb[i * 3 + 1];
        sz[i] = pb[i * 3 + 2];
        sl[i] = ratioL[b * NN + i];
    }
    __syncthreads();
    const int wave = threadIdx.x >> 6, lane = threadIdx.x & 63;
    for (int c = 0; c < 2; ++c) {
        const int col = cbase + wave * 2 + c;
        const float gx = gt[((size_t)b * NM + col) * 3 + 0];
        const float gy = gt[((size_t)b * NM + col) * 3 + 1];
        const float gz = gt[((size_t)b * NM + col) * 3 + 2];
        float acc = 0.0f;
        #pragma unroll 4
        for (int i = lane; i < NN; i += 64) {
            float dx = gx - sx[i], dy = gy - sy[i], dz = gz - sz[i];
            float d2 = dx * dx + dy * dy + dz * dz;
            acc += expf(level * d2) * sl[i];
        }
        #pragma unroll
        for (int o = 1; o < 64; o <<= 1) acc += __shfl_xor(acc, o);
        if (lane == 0) {
            const int idx = b * NM + col;
            const float sr = satr[idx];
            const float ss = sr * acc + EPS_F;
            const float sc = fminf(sr / ss, 1.0f);
            const float rr = sr * sc;
            ratioR[idx] = rr;
            satr[idx] = fmaxf(sr - rr * acc, 0.0f);
        }
    }
}

// finish level j: s1 = sum_m exp(lj*d2)*ratioR[m]; s2 = same with *dist;
//   satl = max(satl - ratioL*s1, 0); cost += ratioL*s2
// start level j+1 (doNext): ratioL = satl_new / (sum_m exp(lnext*d2)*satr_new[m] + eps)
__global__ __launch_bounds__(256) void row_finish(const float* __restrict__ pred,
                                                  const float* __restrict__ gt,
                                                  float* __restrict__ satl,
                                                  float* __restrict__ ratioL,
                                                  const float* __restrict__ ratioR,
                                                  const float* __restrict__ satr,
                                                  float* __restrict__ costAcc,
                                                  float level, float nextLevel, int doNext) {
    __shared__ float sx[NM], sy[NM], sz[NM], srr[NM], snr[NM];
    const int b = blockIdx.x >> 8;
    const int rbase = (blockIdx.x & 255) * 8;
    const float* gtb = gt + (size_t)b * NM * 3;
    for (int i = threadIdx.x; i < NM; i += 256) {
        sx[i] = gtb[i * 3 + 0];
        sy[i] = gtb[i * 3 + 1];
        sz[i] = gtb[i * 3 + 2];
        srr[i] = ratioR[b * NM + i];
        snr[i] = satr[b * NM + i];   // already updated by col_pass this level
    }
    __syncthreads();
    const int wave = threadIdx.x >> 6, lane = threadIdx.x & 63;
    float costw = 0.0f;
    for (int r = 0; r < 2; ++r) {
        const int row = rbase + wave * 2 + r;
        const float px = pred[((size_t)b * NN + row) * 3 + 0];
        const float py = pred[((size_t)b * NN + row) * 3 + 1];
        const float pz = pred[((size_t)b * NN + row) * 3 + 2];
        float s1 = 0.0f, s2 = 0.0f, an = 0.0f;
        #pragma unroll 2
        for (int i = lane; i < NM; i += 64) {
            float dx = px - sx[i], dy = py - sy[i], dz = pz - sz[i];
            float d2 = dx * dx + dy * dy + dz * dz;
            float e = expf(level * d2);
            float t = e * srr[i];
            s1 += t;
            float dist = sqrtf(fmaxf(d2, 1e-12f));
            s2 = fmaf(t, dist, s2);
            if (doNext) an += expf(nextLevel * d2) * snr[i];
        }
        #pragma unroll
        for (int o = 1; o < 64; o <<= 1) {
            s1 += __shfl_xor(s1, o);
            s2 += __shfl_xor(s2, o);
            an += __shfl_xor(an, o);
        }
        if (lane == 0) {
            const int idx = b * NN + row;
            const float rl = ratioL[idx];
            const float nsl = fmaxf(satl[idx] - rl * s1, 0.0f);
            satl[idx] = nsl;
            costw += rl * s2;
            if (doNext) ratioL[idx] = nsl / (an + EPS_F);
        }
    }
    if (lane == 0) atomicAdd(costAcc, costw);
}

__global__ void finalize(const float* __restrict__ costAcc, float* __restrict__ out) {
    out[0] = costAcc[0] * (1.0f / (float)NN);   // radius = 1
}

extern "C" void kernel_launch(void* const* d_in, const int* in_sizes, int n_in,
                              void* d_out, int out_size, void* d_ws, size_t ws_size,
                              hipStream_t stream) {
    const float* pred = (const float*)d_in[0];
    const float* gt   = (const float*)d_in[1];
    float* out = (float*)d_out;

    float* wsf    = (float*)d_ws;
    float* satl   = wsf;
    float* satr   = wsf + NB * NN;
    float* ratioL = wsf + 2 * NB * NN;
    float* ratioR = wsf + 3 * NB * NN;
    float* costAcc = wsf + 4 * NB * NN;

    float levels[11];
    for (int k = 0; k < 10; ++k) levels[k] = -powf(4.0f, (float)(8 - k));
    levels[10] = 0.0f;

    const int rowBlocks = NB * (NN / 8);  // 4096
    const int colBlocks = NB * (NM / 8);  // 4096

    init_state<<<(NB * NN + 255) / 256, 256, 0, stream>>>(satl, satr, costAcc);
    row_start<<<rowBlocks, 256, 0, stream>>>(pred, gt, satl, satr, ratioL, levels[0]);
    for (int j = 0; j < 11; ++j) {
        col_pass<<<colBlocks, 256, 0, stream>>>(pred, gt, ratioL, ratioR, satr, levels[j]);
        const int doNext = (j < 10) ? 1 : 0;
        row_finish<<<rowBlocks, 256, 0, stream>>>(pred, gt, satl, ratioL, ratioR, satr,
                                                  costAcc, levels[j],
                                                  doNext ? levels[j + 1] : 0.0f, doNext);
    }
    finalize<<<1, 1, 0, stream>>>(costAcc, out);
}

// Round 2
// 1062.087 us; speedup vs baseline: 2.9780x; 2.9780x over previous
//
#include <hip/hip_runtime.h>
#include <cmath>

// EMD approxmatch, B=16, N=M=2048, f32.
// Factorized per-level update: nothing [N,M]-shaped is materialized.
// Per level: col_pass (ratioR + satr update), row_finish (cost + satl update,
// fused with next level's row-sum -> ratioL). row_start seeds level 0.
// exp via native v_exp_f32: exp(level*d2) == exp2((level*log2e)*d2).

#define NB 16
#define NN 2048
#define NM 2048
#define EPS_F 1e-9f

#if __has_builtin(__builtin_amdgcn_exp2f)
__device__ __forceinline__ float fast_exp2(float x) { return __builtin_amdgcn_exp2f(x); }
#else
__device__ __forceinline__ float fast_exp2(float x) { return exp2f(x); }
#endif
#if __has_builtin(__builtin_amdgcn_sqrtf)
__device__ __forceinline__ float fast_sqrt(float x) { return __builtin_amdgcn_sqrtf(x); }
#else
__device__ __forceinline__ float fast_sqrt(float x) { return sqrtf(x); }
#endif

__global__ __launch_bounds__(256) void init_state(float* __restrict__ satl,
                                                  float* __restrict__ satr,
                                                  float* __restrict__ costAcc) {
    int i = blockIdx.x * 256 + threadIdx.x;
    if (i < NB * NN) satl[i] = 1.0f;   // factorl = 1
    if (i < NB * NM) satr[i] = 1.0f;   // factorr = 1
    if (i == 0) costAcc[0] = 0.0f;
}

// ratioL[n] = satl[n] / (sum_m exp2(c*d2)*satr[m] + eps)
__global__ __launch_bounds__(256) void row_start(const float* __restrict__ pred,
                                                 const float* __restrict__ gt,
                                                 const float* __restrict__ satl,
                                                 const float* __restrict__ satr,
                                                 float* __restrict__ ratioL,
                                                 float c) {
    __shared__ float4 sg[NM];                    // {x,y,z,satr}
    const int b = blockIdx.x >> 8;               // 256 blocks per batch, 8 rows each
    const int rbase = (blockIdx.x & 255) * 8;
    const float* gtb = gt + (size_t)b * NM * 3;
    for (int i = threadIdx.x; i < NM; i += 256) {
        const float* g = gtb + i * 3;
        sg[i] = make_float4(g[0], g[1], g[2], satr[b * NM + i]);
    }
    __syncthreads();
    const int wave = threadIdx.x >> 6, lane = threadIdx.x & 63;
    const int row0 = rbase + wave * 2;
    const float* p0 = pred + ((size_t)b * NN + row0) * 3;
    const float px0 = p0[0], py0 = p0[1], pz0 = p0[2];
    const float px1 = p0[3], py1 = p0[4], pz1 = p0[5];
    float a0 = 0.0f, a1 = 0.0f;
    for (int i = lane; i < NM; i += 64) {
        float4 g = sg[i];
        float dx = px0 - g.x, dy = py0 - g.y, dz = pz0 - g.z;
        float d2 = dx * dx + dy * dy + dz * dz;
        a0 = fmaf(fast_exp2(c * d2), g.w, a0);
        dx = px1 - g.x; dy = py1 - g.y; dz = pz1 - g.z;
        d2 = dx * dx + dy * dy + dz * dz;
        a1 = fmaf(fast_exp2(c * d2), g.w, a1);
    }
    #pragma unroll
    for (int o = 1; o < 64; o <<= 1) {
        a0 += __shfl_xor(a0, o);
        a1 += __shfl_xor(a1, o);
    }
    if (lane == 0) {
        int idx = b * NN + row0;
        ratioL[idx]     = satl[idx]     / (a0 + EPS_F);
        ratioL[idx + 1] = satl[idx + 1] / (a1 + EPS_F);
    }
}

// sumr[m] = sum_n exp2(c*d2)*ratioL[n];
// ratioR[m] = satr*min(satr/(satr*sumr+eps),1); satr = max(satr - ratioR*sumr, 0)
__global__ __launch_bounds__(256) void col_pass(const float* __restrict__ pred,
                                                const float* __restrict__ gt,
                                                const float* __restrict__ ratioL,
                                                float* __restrict__ ratioR,
                                                float* __restrict__ satr,
                                                float c) {
    __shared__ float4 sp[NN];                    // {x,y,z,ratioL}
    const int b = blockIdx.x >> 8;
    const int cbase = (blockIdx.x & 255) * 8;
    const float* pb = pred + (size_t)b * NN * 3;
    for (int i = threadIdx.x; i < NN; i += 256) {
        const float* p = pb + i * 3;
        sp[i] = make_float4(p[0], p[1], p[2], ratioL[b * NN + i]);
    }
    __syncthreads();
    const int wave = threadIdx.x >> 6, lane = threadIdx.x & 63;
    const int col0 = cbase + wave * 2;
    const float* g0 = gt + ((size_t)b * NM + col0) * 3;
    const float gx0 = g0[0], gy0 = g0[1], gz0 = g0[2];
    const float gx1 = g0[3], gy1 = g0[4], gz1 = g0[5];
    float a0 = 0.0f, a1 = 0.0f;
    for (int i = lane; i < NN; i += 64) {
        float4 p = sp[i];
        float dx = gx0 - p.x, dy = gy0 - p.y, dz = gz0 - p.z;
        float d2 = dx * dx + dy * dy + dz * dz;
        a0 = fmaf(fast_exp2(c * d2), p.w, a0);
        dx = gx1 - p.x; dy = gy1 - p.y; dz = gz1 - p.z;
        d2 = dx * dx + dy * dy + dz * dz;
        a1 = fmaf(fast_exp2(c * d2), p.w, a1);
    }
    #pragma unroll
    for (int o = 1; o < 64; o <<= 1) {
        a0 += __shfl_xor(a0, o);
        a1 += __shfl_xor(a1, o);
    }
    if (lane == 0) {
        #pragma unroll
        for (int t = 0; t < 2; ++t) {
            const int idx = b * NM + col0 + t;
            const float acc = t ? a1 : a0;
            const float sr = satr[idx];
            const float ss = sr * acc + EPS_F;
            const float sc = fminf(sr / ss, 1.0f);
            const float rr = sr * sc;
            ratioR[idx] = rr;
            satr[idx] = fmaxf(sr - rr * acc, 0.0f);
        }
    }
}

// finish level j: s1 = sum_m exp2(c1*d2)*ratioR[m]; s2 = same * dist;
//   satl = max(satl - ratioL*s1, 0); cost += ratioL*s2
// start level j+1: ratioL = satl_new / (sum_m exp2(c2*d2)*satr_new[m] + eps)
__global__ __launch_bounds__(256) void row_finish(const float* __restrict__ pred,
                                                  const float* __restrict__ gt,
                                                  float* __restrict__ satl,
                                                  float* __restrict__ ratioL,
                                                  const float* __restrict__ ratioR,
                                                  const float* __restrict__ satr,
                                                  float* __restrict__ costAcc,
                                                  float c1, float c2, int doNext) {
    __shared__ float4 sg[NM];                    // {x,y,z,ratioR}
    __shared__ float snr[NM];                    // satr (already updated this level)
    __shared__ float wsum[4];
    const int b = blockIdx.x >> 8;
    const int rbase = (blockIdx.x & 255) * 8;
    const float* gtb = gt + (size_t)b * NM * 3;
    for (int i = threadIdx.x; i < NM; i += 256) {
        const float* g = gtb + i * 3;
        sg[i] = make_float4(g[0], g[1], g[2], ratioR[b * NM + i]);
        snr[i] = satr[b * NM + i];
    }
    __syncthreads();
    const int wave = threadIdx.x >> 6, lane = threadIdx.x & 63;
    const int row0 = rbase + wave * 2;
    const float* p0 = pred + ((size_t)b * NN + row0) * 3;
    const float px0 = p0[0], py0 = p0[1], pz0 = p0[2];
    const float px1 = p0[3], py1 = p0[4], pz1 = p0[5];
    float s1_0 = 0.f, s2_0 = 0.f, an_0 = 0.f;
    float s1_1 = 0.f, s2_1 = 0.f, an_1 = 0.f;
    for (int i = lane; i < NM; i += 64) {
        float4 g = sg[i];
        float nr = snr[i];
        // row 0
        float dx = px0 - g.x, dy = py0 - g.y, dz = pz0 - g.z;
        float d2 = dx * dx + dy * dy + dz * dz;
        float t = fast_exp2(c1 * d2) * g.w;
        s1_0 += t;
        float dist = fast_sqrt(fmaxf(d2, 1e-12f));
        s2_0 = fmaf(t, dist, s2_0);
        an_0 = fmaf(fast_exp2(c2 * d2), nr, an_0);
        // row 1
        dx = px1 - g.x; dy = py1 - g.y; dz = pz1 - g.z;
        d2 = dx * dx + dy * dy + dz * dz;
        t = fast_exp2(c1 * d2) * g.w;
        s1_1 += t;
        dist = fast_sqrt(fmaxf(d2, 1e-12f));
        s2_1 = fmaf(t, dist, s2_1);
        an_1 = fmaf(fast_exp2(c2 * d2), nr, an_1);
    }
    #pragma unroll
    for (int o = 1; o < 64; o <<= 1) {
        s1_0 += __shfl_xor(s1_0, o);
        s2_0 += __shfl_xor(s2_0, o);
        an_0 += __shfl_xor(an_0, o);
        s1_1 += __shfl_xor(s1_1, o);
        s2_1 += __shfl_xor(s2_1, o);
        an_1 += __shfl_xor(an_1, o);
    }
    if (lane == 0) {
        float cw = 0.0f;
        const int idx0 = b * NN + row0;
        {
            const float rl = ratioL[idx0];
            const float nsl = fmaxf(satl[idx0] - rl * s1_0, 0.0f);
            satl[idx0] = nsl;
            cw = rl * s2_0;
            if (doNext) ratioL[idx0] = nsl / (an_0 + EPS_F);
        }
        {
            const float rl = ratioL[idx0 + 1];
            const float nsl = fmaxf(satl[idx0 + 1] - rl * s1_1, 0.0f);
            satl[idx0 + 1] = nsl;
            cw += rl * s2_1;
            if (doNext) ratioL[idx0 + 1] = nsl / (an_1 + EPS_F);
        }
        wsum[wave] = cw;
    }
    __syncthreads();
    if (threadIdx.x == 0)
        atomicAdd(costAcc, wsum[0] + wsum[1] + wsum[2] + wsum[3]);
}

__global__ void finalize(const float* __restrict__ costAcc, float* __restrict__ out) {
    out[0] = costAcc[0] * (1.0f / (float)NN);   // radius = 1
}

extern "C" void kernel_launch(void* const* d_in, const int* in_sizes, int n_in,
                              void* d_out, int out_size, void* d_ws, size_t ws_size,
                              hipStream_t stream) {
    const float* pred = (const float*)d_in[0];
    const float* gt   = (const float*)d_in[1];
    float* out = (float*)d_out;

    float* wsf    = (float*)d_ws;
    float* satl   = wsf;
    float* satr   = wsf + NB * NN;
    float* ratioL = wsf + 2 * NB * NN;
    float* ratioR = wsf + 3 * NB * NN;
    float* costAcc = wsf + 4 * NB * NN;

    // c[j] = level_j * log2(e)
    const double LOG2E = 1.4426950408889634;
    float c[11];
    for (int k = 0; k < 10; ++k) c[k] = (float)(-pow(4.0, (double)(8 - k)) * LOG2E);
    c[10] = 0.0f;

    const int rowBlocks = NB * (NN / 8);  // 4096
    const int colBlocks = NB * (NM / 8);  // 4096

    init_state<<<(NB * NN + 255) / 256, 256, 0, stream>>>(satl, satr, costAcc);
    row_start<<<rowBlocks, 256, 0, stream>>>(pred, gt, satl, satr, ratioL, c[0]);
    for (int j = 0; j < 11; ++j) {
        col_pass<<<colBlocks, 256, 0, stream>>>(pred, gt, ratioL, ratioR, satr, c[j]);
        const int doNext = (j < 10) ? 1 : 0;
        row_finish<<<rowBlocks, 256, 0, stream>>>(pred, gt, satl, ratioL, ratioR, satr,
                                                  costAcc, c[j],
                                                  doNext ? c[j + 1] : 0.0f, doNext);
    }
    finalize<<<1, 1, 0, stream>>>(costAcc, out);
}

// Round 3
// 692.244 us; speedup vs baseline: 4.5691x; 1.5343x over previous
//
#include <hip/hip_runtime.h>
#include <cmath>

// EMD approxmatch, B=16, N=M=2048, f32. Factorized per-level update — nothing
// [N,M]-shaped materialized. Per level: col_pass (ratioR + satr), row_finish
// (cost + satl, fused with next level's row-sum -> ratioL).
// exp via v_exp_f32; row_finish uses e1 = (e2^2)^2 with e2 = exp2(c_next*d2)
// since level_j = 4*level_{j+1} exactly (power-of-2 scaling commutes with fp).

#define NB 16
#define NN 2048
#define NM 2048
#define EPS_F 1e-9f

#if __has_builtin(__builtin_amdgcn_exp2f)
__device__ __forceinline__ float fast_exp2(float x) { return __builtin_amdgcn_exp2f(x); }
#else
__device__ __forceinline__ float fast_exp2(float x) { return exp2f(x); }
#endif
#if __has_builtin(__builtin_amdgcn_sqrtf)
__device__ __forceinline__ float fast_sqrt(float x) { return __builtin_amdgcn_sqrtf(x); }
#else
__device__ __forceinline__ float fast_sqrt(float x) { return sqrtf(x); }
#endif

__global__ __launch_bounds__(256) void init_state(float* __restrict__ satl,
                                                  float* __restrict__ satr,
                                                  float* __restrict__ costAcc) {
    int i = blockIdx.x * 256 + threadIdx.x;
    if (i < NB * NN) satl[i] = 1.0f;   // factorl = 1
    if (i < NB * NM) satr[i] = 1.0f;   // factorr = 1
    if (i == 0) costAcc[0] = 0.0f;
}

// ratioL[n] = satl[n] / (sum_m exp2(c*d2)*satr[m] + eps).  16 rows/block, 4/wave.
__global__ __launch_bounds__(256, 4) void row_start(const float* __restrict__ pred,
                                                    const float* __restrict__ gt,
                                                    const float* __restrict__ satl,
                                                    const float* __restrict__ satr,
                                                    float* __restrict__ ratioL,
                                                    float c) {
    __shared__ float4 sg[NM];                    // {x,y,z,satr}
    const int b = blockIdx.x >> 7;               // 128 blocks per batch
    const int rbase = (blockIdx.x & 127) * 16;
    const float* gtb = gt + (size_t)b * NM * 3;
    for (int i = threadIdx.x; i < NM; i += 256) {
        const float* g = gtb + i * 3;
        sg[i] = make_float4(g[0], g[1], g[2], satr[b * NM + i]);
    }
    __syncthreads();
    const int wave = threadIdx.x >> 6, lane = threadIdx.x & 63;
    const int row0 = rbase + wave * 4;
    const float* p0 = pred + ((size_t)b * NN + row0) * 3;
    float px[4], py[4], pz[4], a[4];
    #pragma unroll
    for (int r = 0; r < 4; ++r) {
        px[r] = p0[r * 3 + 0]; py[r] = p0[r * 3 + 1]; pz[r] = p0[r * 3 + 2];
        a[r] = 0.0f;
    }
    #pragma unroll 2
    for (int i = lane; i < NM; i += 64) {
        float4 g = sg[i];
        #pragma unroll
        for (int r = 0; r < 4; ++r) {
            float dx = px[r] - g.x, dy = py[r] - g.y, dz = pz[r] - g.z;
            float d2 = dx * dx + dy * dy + dz * dz;
            a[r] = fmaf(fast_exp2(c * d2), g.w, a[r]);
        }
    }
    #pragma unroll
    for (int o = 1; o < 64; o <<= 1) {
        #pragma unroll
        for (int r = 0; r < 4; ++r) a[r] += __shfl_xor(a[r], o);
    }
    if (lane == 0) {
        const int idx = b * NN + row0;
        #pragma unroll
        for (int r = 0; r < 4; ++r) ratioL[idx + r] = satl[idx + r] / (a[r] + EPS_F);
    }
}

// sumr[m] = sum_n exp2(c*d2)*ratioL[n];
// ratioR[m] = satr*min(satr/(satr*sumr+eps),1); satr = max(satr - ratioR*sumr, 0)
__global__ __launch_bounds__(256, 4) void col_pass(const float* __restrict__ pred,
                                                   const float* __restrict__ gt,
                                                   const float* __restrict__ ratioL,
                                                   float* __restrict__ ratioR,
                                                   float* __restrict__ satr,
                                                   float c) {
    __shared__ float4 sp[NN];                    // {x,y,z,ratioL}
    const int b = blockIdx.x >> 7;
    const int cbase = (blockIdx.x & 127) * 16;
    const float* pb = pred + (size_t)b * NN * 3;
    for (int i = threadIdx.x; i < NN; i += 256) {
        const float* p = pb + i * 3;
        sp[i] = make_float4(p[0], p[1], p[2], ratioL[b * NN + i]);
    }
    __syncthreads();
    const int wave = threadIdx.x >> 6, lane = threadIdx.x & 63;
    const int col0 = cbase + wave * 4;
    const float* g0 = gt + ((size_t)b * NM + col0) * 3;
    float gx[4], gy[4], gz[4], a[4];
    #pragma unroll
    for (int t = 0; t < 4; ++t) {
        gx[t] = g0[t * 3 + 0]; gy[t] = g0[t * 3 + 1]; gz[t] = g0[t * 3 + 2];
        a[t] = 0.0f;
    }
    #pragma unroll 2
    for (int i = lane; i < NN; i += 64) {
        float4 p = sp[i];
        #pragma unroll
        for (int t = 0; t < 4; ++t) {
            float dx = gx[t] - p.x, dy = gy[t] - p.y, dz = gz[t] - p.z;
            float d2 = dx * dx + dy * dy + dz * dz;
            a[t] = fmaf(fast_exp2(c * d2), p.w, a[t]);
        }
    }
    #pragma unroll
    for (int o = 1; o < 64; o <<= 1) {
        #pragma unroll
        for (int t = 0; t < 4; ++t) a[t] += __shfl_xor(a[t], o);
    }
    if (lane == 0) {
        #pragma unroll
        for (int t = 0; t < 4; ++t) {
            const int idx = b * NM + col0 + t;
            const float sr = satr[idx];
            const float ss = sr * a[t] + EPS_F;
            const float sc = fminf(sr / ss, 1.0f);
            const float rr = sr * sc;
            ratioR[idx] = rr;
            satr[idx] = fmaxf(sr - rr * a[t], 0.0f);
        }
    }
}

// MODE 0 (j<=8): e2 = exp2(cq*d2), e1 = (e2^2)^2; an[r] += e2*satr  (cq = c1/4)
// MODE 1 (j==9): e1 = exp2(c1*d2) direct; next level is 0 -> an_all = sum satr
// MODE 2 (j==10): e1 = 1 (level 0); no next level
template <int MODE>
__global__ __launch_bounds__(256, 4) void row_finish(const float* __restrict__ pred,
                                                     const float* __restrict__ gt,
                                                     float* __restrict__ satl,
                                                     float* __restrict__ ratioL,
                                                     const float* __restrict__ ratioR,
                                                     const float* __restrict__ satr,
                                                     float* __restrict__ costAcc,
                                                     float c1, float cq) {
    __shared__ float4 sg[NM];                    // {x,y,z,ratioR}  32768 B
    __shared__ float snr[NM];                    // satr; reused as cost scratch. 8192 B
    const int b = blockIdx.x >> 7;
    const int rbase = (blockIdx.x & 127) * 16;
    const float* gtb = gt + (size_t)b * NM * 3;
    for (int i = threadIdx.x; i < NM; i += 256) {
        const float* g = gtb + i * 3;
        sg[i] = make_float4(g[0], g[1], g[2], ratioR[b * NM + i]);
        if (MODE <= 1) snr[i] = satr[b * NM + i];
    }
    __syncthreads();
    const int wave = threadIdx.x >> 6, lane = threadIdx.x & 63;
    const int row0 = rbase + wave * 4;
    const float* p0 = pred + ((size_t)b * NN + row0) * 3;
    float px[4], py[4], pz[4], s1[4], s2[4], an[4];
    float an_all = 0.0f;
    #pragma unroll
    for (int r = 0; r < 4; ++r) {
        px[r] = p0[r * 3 + 0]; py[r] = p0[r * 3 + 1]; pz[r] = p0[r * 3 + 2];
        s1[r] = 0.0f; s2[r] = 0.0f; an[r] = 0.0f;
    }
    #pragma unroll 2
    for (int i = lane; i < NM; i += 64) {
        float4 g = sg[i];
        float nr = (MODE <= 1) ? snr[i] : 0.0f;
        #pragma unroll
        for (int r = 0; r < 4; ++r) {
            float dx = px[r] - g.x, dy = py[r] - g.y, dz = pz[r] - g.z;
            float d2 = dx * dx + dy * dy + dz * dz;
            float e1;
            if (MODE == 0) {
                float e2 = fast_exp2(cq * d2);
                float e22 = e2 * e2;
                e1 = e22 * e22;
                an[r] = fmaf(e2, nr, an[r]);
            } else if (MODE == 1) {
                e1 = fast_exp2(c1 * d2);
            } else {
                e1 = 1.0f;
            }
            float t = e1 * g.w;
            s1[r] += t;
            float dist = fast_sqrt(fmaxf(d2, 1e-12f));
            s2[r] = fmaf(t, dist, s2[r]);
        }
        if (MODE == 1) an_all += nr;
    }
    #pragma unroll
    for (int o = 1; o < 64; o <<= 1) {
        #pragma unroll
        for (int r = 0; r < 4; ++r) {
            s1[r] += __shfl_xor(s1[r], o);
            s2[r] += __shfl_xor(s2[r], o);
            if (MODE == 0) an[r] += __shfl_xor(an[r], o);
        }
        if (MODE == 1) an_all += __shfl_xor(an_all, o);
    }
    float cw = 0.0f;
    if (lane == 0) {
        const int idx = b * NN + row0;
        #pragma unroll
        for (int r = 0; r < 4; ++r) {
            const float rl = ratioL[idx + r];
            const float nsl = fmaxf(satl[idx + r] - rl * s1[r], 0.0f);
            satl[idx + r] = nsl;
            cw += rl * s2[r];
            if (MODE == 0) ratioL[idx + r] = nsl / (an[r] + EPS_F);
            else if (MODE == 1) ratioL[idx + r] = nsl / (an_all + EPS_F);
        }
    }
    __syncthreads();                 // all reads of snr done
    if (lane == 0) snr[wave] = cw;   // reuse snr as cross-wave scratch
    __syncthreads();
    if (threadIdx.x == 0)
        atomicAdd(costAcc, snr[0] + snr[1] + snr[2] + snr[3]);
}

__global__ void finalize(const float* __restrict__ costAcc, float* __restrict__ out) {
    out[0] = costAcc[0] * (1.0f / (float)NN);   // radius = 1
}

extern "C" void kernel_launch(void* const* d_in, const int* in_sizes, int n_in,
                              void* d_out, int out_size, void* d_ws, size_t ws_size,
                              hipStream_t stream) {
    const float* pred = (const float*)d_in[0];
    const float* gt   = (const float*)d_in[1];
    float* out = (float*)d_out;

    float* wsf    = (float*)d_ws;
    float* satl   = wsf;
    float* satr   = wsf + NB * NN;
    float* ratioL = wsf + 2 * NB * NN;
    float* ratioR = wsf + 3 * NB * NN;
    float* costAcc = wsf + 4 * NB * NN;

    // c[j] = level_j * log2(e); c[j+1] = c[j]/4 exactly for j<=8
    const double LOG2E = 1.4426950408889634;
    float c[11];
    for (int k = 0; k < 10; ++k) c[k] = (float)(-pow(4.0, (double)(8 - k)) * LOG2E);
    c[10] = 0.0f;

    const int blocks = NB * (NN / 16);  // 2048

    init_state<<<(NB * NN + 255) / 256, 256, 0, stream>>>(satl, satr, costAcc);
    row_start<<<blocks, 256, 0, stream>>>(pred, gt, satl, satr, ratioL, c[0]);
    for (int j = 0; j < 11; ++j) {
        col_pass<<<blocks, 256, 0, stream>>>(pred, gt, ratioL, ratioR, satr, c[j]);
        if (j <= 8)
            row_finish<0><<<blocks, 256, 0, stream>>>(pred, gt, satl, ratioL, ratioR, satr,
                                                      costAcc, c[j], c[j + 1]);
        else if (j == 9)
            row_finish<1><<<blocks, 256, 0, stream>>>(pred, gt, satl, ratioL, ratioR, satr,
                                                      costAcc, c[j], 0.0f);
        else
            row_finish<2><<<blocks, 256, 0, stream>>>(pred, gt, satl, ratioL, ratioR, satr,
                                                      costAcc, 0.0f, 0.0f);
    }
    finalize<<<1, 1, 0, stream>>>(costAcc, out);
}

// Round 4
// 632.139 us; speedup vs baseline: 5.0035x; 1.0951x over previous
//
#include <hip/hip_runtime.h>
#include <cmath>

// EMD approxmatch, B=16, N=M=2048, f32. Factorized per-level update — nothing
// [N,M]-shaped materialized. Per level: col_pass (ratioR + satr), row_finish
// (cost + satl, fused with next level's row-sum -> ratioL).
// exp via v_exp_f32; row_finish MODE0 uses e1 = (e2^2)^2 with e2 = exp2(cq*d2),
// cq = c/4 (levels scale by exactly 4). 8 rows per wave, 32 per block,
// grid = 1024 = 256 CU x 4 resident blocks (LDS 40960 = 160KiB/4).

#define NB 16
#define NN 2048
#define NM 2048
#define EPS_F 1e-9f

#if __has_builtin(__builtin_amdgcn_exp2f)
__device__ __forceinline__ float fast_exp2(float x) { return __builtin_amdgcn_exp2f(x); }
#else
__device__ __forceinline__ float fast_exp2(float x) { return exp2f(x); }
#endif
#if __has_builtin(__builtin_amdgcn_sqrtf)
__device__ __forceinline__ float fast_sqrt(float x) { return __builtin_amdgcn_sqrtf(x); }
#else
__device__ __forceinline__ float fast_sqrt(float x) { return sqrtf(x); }
#endif

__global__ __launch_bounds__(256) void init_state(float* __restrict__ satl,
                                                  float* __restrict__ satr,
                                                  float* __restrict__ costAcc) {
    int i = blockIdx.x * 256 + threadIdx.x;
    if (i < NB * NN) satl[i] = 1.0f;   // factorl = 1
    if (i < NB * NM) satr[i] = 1.0f;   // factorr = 1
    if (i == 0) costAcc[0] = 0.0f;
}

// ratioL[n] = satl[n] / (sum_m exp2(c*d2)*satr[m] + eps).  32 rows/block, 8/wave.
__global__ __launch_bounds__(256, 4) void row_start(const float* __restrict__ pred,
                                                    const float* __restrict__ gt,
                                                    const float* __restrict__ satl,
                                                    const float* __restrict__ satr,
                                                    float* __restrict__ ratioL,
                                                    float c) {
    __shared__ float4 sg[NM];                    // {x,y,z,satr}
    const int b = blockIdx.x >> 6;               // 64 blocks per batch
    const int rbase = (blockIdx.x & 63) * 32;
    const float* gtb = gt + (size_t)b * NM * 3;
    for (int i = threadIdx.x; i < NM; i += 256) {
        const float* g = gtb + i * 3;
        sg[i] = make_float4(g[0], g[1], g[2], satr[b * NM + i]);
    }
    __syncthreads();
    const int wave = threadIdx.x >> 6, lane = threadIdx.x & 63;
    const int row0 = rbase + wave * 8;
    const float* p0 = pred + ((size_t)b * NN + row0) * 3;
    float px[8], py[8], pz[8], a[8];
    #pragma unroll
    for (int r = 0; r < 8; ++r) {
        px[r] = p0[r * 3 + 0]; py[r] = p0[r * 3 + 1]; pz[r] = p0[r * 3 + 2];
        a[r] = 0.0f;
    }
    #pragma unroll 2
    for (int i = lane; i < NM; i += 64) {
        float4 g = sg[i];
        #pragma unroll
        for (int r = 0; r < 8; ++r) {
            float dx = px[r] - g.x, dy = py[r] - g.y, dz = pz[r] - g.z;
            float d2 = fmaf(dz, dz, fmaf(dy, dy, dx * dx));
            a[r] = fmaf(fast_exp2(c * d2), g.w, a[r]);
        }
    }
    #pragma unroll
    for (int o = 1; o < 64; o <<= 1) {
        #pragma unroll
        for (int r = 0; r < 8; ++r) a[r] += __shfl_xor(a[r], o);
    }
    if (lane == 0) {
        const int idx = b * NN + row0;
        #pragma unroll
        for (int r = 0; r < 8; ++r) ratioL[idx + r] = satl[idx + r] / (a[r] + EPS_F);
    }
}

// sumr[m] = sum_n exp2(c*d2)*ratioL[n];
// ratioR[m] = satr*min(satr/(satr*sumr+eps),1); satr = max(satr - ratioR*sumr, 0)
__global__ __launch_bounds__(256, 4) void col_pass(const float* __restrict__ pred,
                                                   const float* __restrict__ gt,
                                                   const float* __restrict__ ratioL,
                                                   float* __restrict__ ratioR,
                                                   float* __restrict__ satr,
                                                   float c) {
    __shared__ float4 sp[NN];                    // {x,y,z,ratioL}
    const int b = blockIdx.x >> 6;
    const int cbase = (blockIdx.x & 63) * 32;
    const float* pb = pred + (size_t)b * NN * 3;
    for (int i = threadIdx.x; i < NN; i += 256) {
        const float* p = pb + i * 3;
        sp[i] = make_float4(p[0], p[1], p[2], ratioL[b * NN + i]);
    }
    __syncthreads();
    const int wave = threadIdx.x >> 6, lane = threadIdx.x & 63;
    const int col0 = cbase + wave * 8;
    const float* g0 = gt + ((size_t)b * NM + col0) * 3;
    float gx[8], gy[8], gz[8], a[8];
    #pragma unroll
    for (int t = 0; t < 8; ++t) {
        gx[t] = g0[t * 3 + 0]; gy[t] = g0[t * 3 + 1]; gz[t] = g0[t * 3 + 2];
        a[t] = 0.0f;
    }
    #pragma unroll 2
    for (int i = lane; i < NN; i += 64) {
        float4 p = sp[i];
        #pragma unroll
        for (int t = 0; t < 8; ++t) {
            float dx = gx[t] - p.x, dy = gy[t] - p.y, dz = gz[t] - p.z;
            float d2 = fmaf(dz, dz, fmaf(dy, dy, dx * dx));
            a[t] = fmaf(fast_exp2(c * d2), p.w, a[t]);
        }
    }
    #pragma unroll
    for (int o = 1; o < 64; o <<= 1) {
        #pragma unroll
        for (int t = 0; t < 8; ++t) a[t] += __shfl_xor(a[t], o);
    }
    if (lane == 0) {
        #pragma unroll
        for (int t = 0; t < 8; ++t) {
            const int idx = b * NM + col0 + t;
            const float sr = satr[idx];
            const float ss = sr * a[t] + EPS_F;
            const float sc = fminf(sr / ss, 1.0f);
            const float rr = sr * sc;
            ratioR[idx] = rr;
            satr[idx] = fmaxf(sr - rr * a[t], 0.0f);
        }
    }
}

// Last level (exp == 1): per-col sum is column-independent = sum_n ratioL[n].
// One block per batch; satr update is dead (nothing reads it afterwards).
__global__ __launch_bounds__(256) void col_last(const float* __restrict__ ratioL,
                                                float* __restrict__ ratioR,
                                                const float* __restrict__ satr) {
    __shared__ float part[256];
    const int b = blockIdx.x;
    float acc = 0.0f;
    for (int i = threadIdx.x; i < NN; i += 256) acc += ratioL[b * NN + i];
    part[threadIdx.x] = acc;
    __syncthreads();
    for (int s = 128; s > 0; s >>= 1) {
        if (threadIdx.x < s) part[threadIdx.x] += part[threadIdx.x + s];
        __syncthreads();
    }
    const float sumRL = part[0];
    for (int m = threadIdx.x; m < NM; m += 256) {
        const int idx = b * NM + m;
        const float sr = satr[idx];
        const float ss = sr * sumRL + EPS_F;
        const float sc = fminf(sr / ss, 1.0f);
        ratioR[idx] = sr * sc;
    }
}

// MODE 0 (j<=8): e2 = exp2(cq*d2), e1 = (e2^2)^2; an[r] += e2*satr  (cq = c1/4)
// MODE 1 (j==9): e1 = exp2(c1*d2); next level 0 -> an_all = sum satr
// MODE 2 (j==10): e1 = 1; cost only (satl update dead)
template <int MODE>
__global__ __launch_bounds__(256, 4) void row_finish(const float* __restrict__ pred,
                                                     const float* __restrict__ gt,
                                                     float* __restrict__ satl,
                                                     float* __restrict__ ratioL,
                                                     const float* __restrict__ ratioR,
                                                     const float* __restrict__ satr,
                                                     float* __restrict__ costAcc,
                                                     float c1, float cq) {
    __shared__ float4 sg[NM];                    // {x,y,z,ratioR}  32768 B
    __shared__ float snr[NM];                    // satr; reused as cost scratch. 8192 B
    const int b = blockIdx.x >> 6;
    const int rbase = (blockIdx.x & 63) * 32;
    const float* gtb = gt + (size_t)b * NM * 3;
    for (int i = threadIdx.x; i < NM; i += 256) {
        const float* g = gtb + i * 3;
        sg[i] = make_float4(g[0], g[1], g[2], ratioR[b * NM + i]);
        if (MODE <= 1) snr[i] = satr[b * NM + i];
    }
    __syncthreads();
    const int wave = threadIdx.x >> 6, lane = threadIdx.x & 63;
    const int row0 = rbase + wave * 8;
    const float* p0 = pred + ((size_t)b * NN + row0) * 3;
    float px[8], py[8], pz[8], s1[8], s2[8], an[8];
    float an_all = 0.0f;
    #pragma unroll
    for (int r = 0; r < 8; ++r) {
        px[r] = p0[r * 3 + 0]; py[r] = p0[r * 3 + 1]; pz[r] = p0[r * 3 + 2];
        s1[r] = 0.0f; s2[r] = 0.0f; an[r] = 0.0f;
    }
    #pragma unroll 2
    for (int i = lane; i < NM; i += 64) {
        float4 g = sg[i];
        float nr = (MODE <= 1) ? snr[i] : 0.0f;
        #pragma unroll
        for (int r = 0; r < 8; ++r) {
            float dx = px[r] - g.x, dy = py[r] - g.y, dz = pz[r] - g.z;
            float d2 = fmaf(dz, dz, fmaf(dy, dy, dx * dx));
            float e1;
            if (MODE == 0) {
                float e2 = fast_exp2(cq * d2);
                float e22 = e2 * e2;
                e1 = e22 * e22;
                an[r] = fmaf(e2, nr, an[r]);
            } else if (MODE == 1) {
                e1 = fast_exp2(c1 * d2);
            } else {
                e1 = 1.0f;
            }
            float dist = fast_sqrt(d2);
            if (MODE == 2) {
                s2[r] = fmaf(g.w, dist, s2[r]);
            } else {
                float t = e1 * g.w;
                s1[r] += t;
                s2[r] = fmaf(t, dist, s2[r]);
            }
        }
        if (MODE == 1) an_all += nr;
    }
    #pragma unroll
    for (int o = 1; o < 64; o <<= 1) {
        #pragma unroll
        for (int r = 0; r < 8; ++r) {
            if (MODE <= 1) s1[r] += __shfl_xor(s1[r], o);
            s2[r] += __shfl_xor(s2[r], o);
            if (MODE == 0) an[r] += __shfl_xor(an[r], o);
        }
        if (MODE == 1) an_all += __shfl_xor(an_all, o);
    }
    float cw = 0.0f;
    if (lane == 0) {
        const int idx = b * NN + row0;
        #pragma unroll
        for (int r = 0; r < 8; ++r) {
            const float rl = ratioL[idx + r];
            if (MODE == 2) {
                cw += rl * s2[r];
            } else {
                const float nsl = fmaxf(satl[idx + r] - rl * s1[r], 0.0f);
                satl[idx + r] = nsl;
                cw += rl * s2[r];
                if (MODE == 0) ratioL[idx + r] = nsl / (an[r] + EPS_F);
                else ratioL[idx + r] = nsl / (an_all + EPS_F);
            }
        }
    }
    __syncthreads();                 // all reads of snr done
    if (lane == 0) snr[wave] = cw;   // reuse snr as cross-wave scratch
    __syncthreads();
    if (threadIdx.x == 0)
        atomicAdd(costAcc, snr[0] + snr[1] + snr[2] + snr[3]);
}

__global__ void finalize(const float* __restrict__ costAcc, float* __restrict__ out) {
    out[0] = costAcc[0] * (1.0f / (float)NN);   // radius = 1
}

extern "C" void kernel_launch(void* const* d_in, const int* in_sizes, int n_in,
                              void* d_out, int out_size, void* d_ws, size_t ws_size,
                              hipStream_t stream) {
    const float* pred = (const float*)d_in[0];
    const float* gt   = (const float*)d_in[1];
    float* out = (float*)d_out;

    float* wsf    = (float*)d_ws;
    float* satl   = wsf;
    float* satr   = wsf + NB * NN;
    float* ratioL = wsf + 2 * NB * NN;
    float* ratioR = wsf + 3 * NB * NN;
    float* costAcc = wsf + 4 * NB * NN;

    // c[j] = level_j * log2(e); c[j+1] = c[j]/4 exactly for j<=8
    const double LOG2E = 1.4426950408889634;
    float c[11];
    for (int k = 0; k < 10; ++k) c[k] = (float)(-pow(4.0, (double)(8 - k)) * LOG2E);
    c[10] = 0.0f;

    const int blocks = NB * (NN / 32);  // 1024 = 256 CU x 4 resident

    init_state<<<(NB * NN + 255) / 256, 256, 0, stream>>>(satl, satr, costAcc);
    row_start<<<blocks, 256, 0, stream>>>(pred, gt, satl, satr, ratioL, c[0]);
    for (int j = 0; j <= 8; ++j) {
        col_pass<<<blocks, 256, 0, stream>>>(pred, gt, ratioL, ratioR, satr, c[j]);
        row_finish<0><<<blocks, 256, 0, stream>>>(pred, gt, satl, ratioL, ratioR, satr,
                                                  costAcc, c[j], c[j + 1]);
    }
    col_pass<<<blocks, 256, 0, stream>>>(pred, gt, ratioL, ratioR, satr, c[9]);
    row_finish<1><<<blocks, 256, 0, stream>>>(pred, gt, satl, ratioL, ratioR, satr,
                                              costAcc, c[9], 0.0f);
    col_last<<<NB, 256, 0, stream>>>(ratioL, ratioR, satr);
    row_finish<2><<<blocks, 256, 0, stream>>>(pred, gt, satl, ratioL, ratioR, satr,
                                              costAcc, 0.0f, 0.0f);
    finalize<<<1, 1, 0, stream>>>(costAcc, out);
}

// Round 5
// 631.192 us; speedup vs baseline: 5.0110x; 1.0015x over previous
//
#include <hip/hip_runtime.h>
#include <cmath>

// EMD approxmatch, B=16, N=M=2048, f32. Factorized per-level update — nothing
// [N,M]-shaped materialized. Per level: col_pass (ratioR + satr), row_finish
// (cost + satl, fused with next level's row-sum -> ratioL).
// This round: dot-form d2 = |p|^2+|g|^2-2p.g (4 ops) and packed-FP32 via
// float2 ext-vectors over the i-dimension (SoA LDS tiles) -> v_pk_fma_f32.
// exp via v_exp_f32; row_finish MODE0 e1 = (e2^2)^2, e2 = exp2(cq*d2), cq=c/4.

#define NB 16
#define NN 2048
#define NM 2048
#define EPS_F 1e-9f
#define NH 1024   // pair-count (i dimension packed by 2)

typedef float v2f __attribute__((ext_vector_type(2)));

__device__ __forceinline__ v2f v2(float s) { v2f r; r.x = s; r.y = s; return r; }
__device__ __forceinline__ v2f vfma(v2f a, v2f b, v2f c) { return __builtin_elementwise_fma(a, b, c); }
__device__ __forceinline__ v2f vmax(v2f a, v2f b) { return __builtin_elementwise_max(a, b); }
__device__ __forceinline__ v2f vmin(v2f a, v2f b) { return __builtin_elementwise_min(a, b); }

#if __has_builtin(__builtin_amdgcn_exp2f)
__device__ __forceinline__ float fast_exp2(float x) { return __builtin_amdgcn_exp2f(x); }
#else
__device__ __forceinline__ float fast_exp2(float x) { return exp2f(x); }
#endif
#if __has_builtin(__builtin_amdgcn_sqrtf)
__device__ __forceinline__ float fast_sqrt(float x) { return __builtin_amdgcn_sqrtf(x); }
#else
__device__ __forceinline__ float fast_sqrt(float x) { return sqrtf(x); }
#endif

__device__ __forceinline__ v2f vexp2(v2f a) {
    v2f r; r.x = fast_exp2(a.x); r.y = fast_exp2(a.y); return r;
}
__device__ __forceinline__ v2f vsqrt(v2f a) {
    v2f r; r.x = fast_sqrt(a.x); r.y = fast_sqrt(a.y); return r;
}

__global__ __launch_bounds__(256) void init_state(float* __restrict__ satl,
                                                  float* __restrict__ satr,
                                                  float* __restrict__ costAcc) {
    int i = blockIdx.x * 256 + threadIdx.x;
    if (i < NB * NN) satl[i] = 1.0f;   // factorl = 1
    if (i < NB * NM) satr[i] = 1.0f;   // factorr = 1
    if (i == 0) costAcc[0] = 0.0f;
}

// ratioL[n] = satl[n] / (sum_m exp2(c*d2)*satr[m] + eps).  16 rows/block, 4/wave.
__global__ __launch_bounds__(256, 4) void row_start(const float* __restrict__ pred,
                                                    const float* __restrict__ gt,
                                                    const float* __restrict__ satl,
                                                    const float* __restrict__ satr,
                                                    float* __restrict__ ratioL,
                                                    float c) {
    __shared__ v2f sgx[NH], sgy[NH], sgz[NH], sgw[NH];   // gt SoA pairs + satr
    const int b = blockIdx.x >> 7;                // 128 blocks per batch
    const int rbase = (blockIdx.x & 127) * 16;
    const float* gtb = gt + (size_t)b * NM * 3;
    for (int i = threadIdx.x; i < NH; i += 256) {
        const float* g = gtb + i * 6;
        sgx[i] = (v2f){g[0], g[3]};
        sgy[i] = (v2f){g[1], g[4]};
        sgz[i] = (v2f){g[2], g[5]};
        sgw[i] = *(const v2f*)(satr + b * NM + 2 * i);
    }
    __syncthreads();
    const int wave = threadIdx.x >> 6, lane = threadIdx.x & 63;
    const int row0 = rbase + wave * 4;
    const float* p0 = pred + ((size_t)b * NN + row0) * 3;
    float qx[4], qy[4], qz[4], cb[4];
    v2f a[4];
    #pragma unroll
    for (int r = 0; r < 4; ++r) {
        float px = p0[r * 3 + 0], py = p0[r * 3 + 1], pz = p0[r * 3 + 2];
        qx[r] = -2.0f * c * px; qy[r] = -2.0f * c * py; qz[r] = -2.0f * c * pz;
        cb[r] = c * (px * px + py * py + pz * pz);
        a[r] = v2(0.0f);
    }
    for (int i = lane; i < NH; i += 64) {
        v2f gx2 = sgx[i], gy2 = sgy[i], gz2 = sgz[i], sr2 = sgw[i];
        v2f cg2 = vfma(gx2, gx2, vfma(gy2, gy2, gz2 * gz2)) * v2(c);
        #pragma unroll
        for (int r = 0; r < 4; ++r) {
            v2f arg = vfma(v2(qx[r]), gx2, vfma(v2(qy[r]), gy2,
                      vfma(v2(qz[r]), gz2, cg2 + v2(cb[r]))));
            arg = vmin(arg, v2(0.0f));
            a[r] = vfma(vexp2(arg), sr2, a[r]);
        }
    }
    float as[4];
    #pragma unroll
    for (int r = 0; r < 4; ++r) as[r] = a[r].x + a[r].y;
    #pragma unroll
    for (int o = 1; o < 64; o <<= 1) {
        #pragma unroll
        for (int r = 0; r < 4; ++r) as[r] += __shfl_xor(as[r], o);
    }
    if (lane == 0) {
        const int idx = b * NN + row0;
        #pragma unroll
        for (int r = 0; r < 4; ++r) ratioL[idx + r] = satl[idx + r] / (as[r] + EPS_F);
    }
}

// ss[m] = sum_n exp2(c*d2)*ratioL[n];
// ratioR[m] = satr*min(satr/(satr*ss+eps),1); satr = max(satr - ratioR*ss, 0)
__global__ __launch_bounds__(256, 4) void col_pass(const float* __restrict__ pred,
                                                   const float* __restrict__ gt,
                                                   const float* __restrict__ ratioL,
                                                   float* __restrict__ ratioR,
                                                   float* __restrict__ satr,
                                                   float c) {
    __shared__ v2f spx[NH], spy[NH], spz[NH], spw[NH];   // pred SoA pairs + ratioL
    const int b = blockIdx.x >> 7;
    const int cbase = (blockIdx.x & 127) * 16;
    const float* pb = pred + (size_t)b * NN * 3;
    for (int i = threadIdx.x; i < NH; i += 256) {
        const float* p = pb + i * 6;
        spx[i] = (v2f){p[0], p[3]};
        spy[i] = (v2f){p[1], p[4]};
        spz[i] = (v2f){p[2], p[5]};
        spw[i] = *(const v2f*)(ratioL + b * NN + 2 * i);
    }
    __syncthreads();
    const int wave = threadIdx.x >> 6, lane = threadIdx.x & 63;
    const int col0 = cbase + wave * 4;
    const float* g0 = gt + ((size_t)b * NM + col0) * 3;
    float mx[4], my[4], mz[4], cb[4];
    v2f a[4];
    #pragma unroll
    for (int t = 0; t < 4; ++t) {
        float gx = g0[t * 3 + 0], gy = g0[t * 3 + 1], gz = g0[t * 3 + 2];
        mx[t] = -2.0f * c * gx; my[t] = -2.0f * c * gy; mz[t] = -2.0f * c * gz;
        cb[t] = c * (gx * gx + gy * gy + gz * gz);
        a[t] = v2(0.0f);
    }
    for (int i = lane; i < NH; i += 64) {
        v2f px2 = spx[i], py2 = spy[i], pz2 = spz[i], rl2 = spw[i];
        v2f cp2 = vfma(px2, px2, vfma(py2, py2, pz2 * pz2)) * v2(c);
        #pragma unroll
        for (int t = 0; t < 4; ++t) {
            v2f arg = vfma(v2(mx[t]), px2, vfma(v2(my[t]), py2,
                      vfma(v2(mz[t]), pz2, cp2 + v2(cb[t]))));
            arg = vmin(arg, v2(0.0f));
            a[t] = vfma(vexp2(arg), rl2, a[t]);
        }
    }
    float as[4];
    #pragma unroll
    for (int t = 0; t < 4; ++t) as[t] = a[t].x + a[t].y;
    #pragma unroll
    for (int o = 1; o < 64; o <<= 1) {
        #pragma unroll
        for (int t = 0; t < 4; ++t) as[t] += __shfl_xor(as[t], o);
    }
    if (lane == 0) {
        #pragma unroll
        for (int t = 0; t < 4; ++t) {
            const int idx = b * NM + col0 + t;
            const float sr = satr[idx];
            const float ss = sr * as[t] + EPS_F;
            const float sc = fminf(sr / ss, 1.0f);
            const float rr = sr * sc;
            ratioR[idx] = rr;
            satr[idx] = fmaxf(sr - rr * as[t], 0.0f);
        }
    }
}

// Last level (exp == 1): col sum is column-independent = sum_n ratioL[n].
__global__ __launch_bounds__(256) void col_last(const float* __restrict__ ratioL,
                                                float* __restrict__ ratioR,
                                                const float* __restrict__ satr) {
    __shared__ float part[256];
    const int b = blockIdx.x;
    float acc = 0.0f;
    for (int i = threadIdx.x; i < NN; i += 256) acc += ratioL[b * NN + i];
    part[threadIdx.x] = acc;
    __syncthreads();
    for (int s = 128; s > 0; s >>= 1) {
        if (threadIdx.x < s) part[threadIdx.x] += part[threadIdx.x + s];
        __syncthreads();
    }
    const float sumRL = part[0];
    for (int m = threadIdx.x; m < NM; m += 256) {
        const int idx = b * NM + m;
        const float sr = satr[idx];
        const float ss = sr * sumRL + EPS_F;
        ratioR[idx] = sr * fminf(sr / ss, 1.0f);
    }
}

// MODE 0 (j<=8): e2 = exp2(cq*d2), e1 = (e2^2)^2; an[r] += e2*satr  (cq = c1/4)
// MODE 1 (j==9): e1 = exp2(c1*d2); next level 0 -> an_all = sum satr
// MODE 2 (j==10): e1 = 1; cost only (satl update dead)
template <int MODE>
__global__ __launch_bounds__(256, 4) void row_finish(const float* __restrict__ pred,
                                                     const float* __restrict__ gt,
                                                     float* __restrict__ satl,
                                                     float* __restrict__ ratioL,
                                                     const float* __restrict__ ratioR,
                                                     const float* __restrict__ satr,
                                                     float* __restrict__ costAcc,
                                                     float c1, float cq) {
    __shared__ v2f sgx[NH], sgy[NH], sgz[NH], sgw[NH], snr[NH];  // 40960 B exactly
    const int b = blockIdx.x >> 7;
    const int rbase = (blockIdx.x & 127) * 16;
    const float* gtb = gt + (size_t)b * NM * 3;
    for (int i = threadIdx.x; i < NH; i += 256) {
        const float* g = gtb + i * 6;
        sgx[i] = (v2f){g[0], g[3]};
        sgy[i] = (v2f){g[1], g[4]};
        sgz[i] = (v2f){g[2], g[5]};
        sgw[i] = *(const v2f*)(ratioR + b * NM + 2 * i);
        if (MODE <= 1) snr[i] = *(const v2f*)(satr + b * NM + 2 * i);
    }
    __syncthreads();
    const int wave = threadIdx.x >> 6, lane = threadIdx.x & 63;
    const int row0 = rbase + wave * 4;
    const float* p0 = pred + ((size_t)b * NN + row0) * 3;
    float nx[4], ny[4], nz[4], p2[4];
    v2f s1[4], s2[4], an[4], an_all = v2(0.0f);
    #pragma unroll
    for (int r = 0; r < 4; ++r) {
        float px = p0[r * 3 + 0], py = p0[r * 3 + 1], pz = p0[r * 3 + 2];
        nx[r] = -2.0f * px; ny[r] = -2.0f * py; nz[r] = -2.0f * pz;
        p2[r] = px * px + py * py + pz * pz;
        s1[r] = v2(0.0f); s2[r] = v2(0.0f); an[r] = v2(0.0f);
    }
    for (int i = lane; i < NH; i += 64) {
        v2f gx2 = sgx[i], gy2 = sgy[i], gz2 = sgz[i], rr2 = sgw[i];
        v2f nr2 = (MODE <= 1) ? snr[i] : v2(0.0f);
        v2f g2 = vfma(gx2, gx2, vfma(gy2, gy2, gz2 * gz2));
        #pragma unroll
        for (int r = 0; r < 4; ++r) {
            v2f d2 = vfma(v2(nx[r]), gx2, vfma(v2(ny[r]), gy2,
                     vfma(v2(nz[r]), gz2, g2 + v2(p2[r]))));
            d2 = vmax(d2, v2(0.0f));
            v2f dist = vsqrt(d2);
            v2f t;
            if (MODE == 0) {
                v2f e2 = vexp2(d2 * v2(cq));
                v2f e22 = e2 * e2;
                an[r] = vfma(e2, nr2, an[r]);
                t = (e22 * e22) * rr2;
                s1[r] += t;
            } else if (MODE == 1) {
                t = vexp2(d2 * v2(c1)) * rr2;
                s1[r] += t;
            } else {
                t = rr2;
            }
            s2[r] = vfma(t, dist, s2[r]);
        }
        if (MODE == 1) an_all += nr2;
    }
    float S1[4], S2[4], AN[4], ANA = an_all.x + an_all.y;
    #pragma unroll
    for (int r = 0; r < 4; ++r) {
        S1[r] = s1[r].x + s1[r].y;
        S2[r] = s2[r].x + s2[r].y;
        AN[r] = an[r].x + an[r].y;
    }
    #pragma unroll
    for (int o = 1; o < 64; o <<= 1) {
        #pragma unroll
        for (int r = 0; r < 4; ++r) {
            if (MODE <= 1) S1[r] += __shfl_xor(S1[r], o);
            S2[r] += __shfl_xor(S2[r], o);
            if (MODE == 0) AN[r] += __shfl_xor(AN[r], o);
        }
        if (MODE == 1) ANA += __shfl_xor(ANA, o);
    }
    float cw = 0.0f;
    if (lane == 0) {
        const int idx = b * NN + row0;
        #pragma unroll
        for (int r = 0; r < 4; ++r) {
            const float rl = ratioL[idx + r];
            if (MODE == 2) {
                cw += rl * S2[r];
            } else {
                const float nsl = fmaxf(satl[idx + r] - rl * S1[r], 0.0f);
                satl[idx + r] = nsl;
                cw += rl * S2[r];
                if (MODE == 0) ratioL[idx + r] = nsl / (AN[r] + EPS_F);
                else ratioL[idx + r] = nsl / (ANA + EPS_F);
            }
        }
    }
    __syncthreads();                            // all reads of snr done
    float* scratch = (float*)snr;               // reuse as cross-wave scratch
    if (lane == 0) scratch[wave] = cw;
    __syncthreads();
    if (threadIdx.x == 0)
        atomicAdd(costAcc, scratch[0] + scratch[1] + scratch[2] + scratch[3]);
}

__global__ void finalize(const float* __restrict__ costAcc, float* __restrict__ out) {
    out[0] = costAcc[0] * (1.0f / (float)NN);   // radius = 1
}

extern "C" void kernel_launch(void* const* d_in, const int* in_sizes, int n_in,
                              void* d_out, int out_size, void* d_ws, size_t ws_size,
                              hipStream_t stream) {
    const float* pred = (const float*)d_in[0];
    const float* gt   = (const float*)d_in[1];
    float* out = (float*)d_out;

    float* wsf    = (float*)d_ws;
    float* satl   = wsf;
    float* satr   = wsf + NB * NN;
    float* ratioL = wsf + 2 * NB * NN;
    float* ratioR = wsf + 3 * NB * NN;
    float* costAcc = wsf + 4 * NB * NN;

    // c[j] = level_j * log2(e); c[j+1] = c[j]/4 exactly for j<=8
    const double LOG2E = 1.4426950408889634;
    float c[11];
    for (int k = 0; k < 10; ++k) c[k] = (float)(-pow(4.0, (double)(8 - k)) * LOG2E);
    c[10] = 0.0f;

    const int blocks = NB * (NN / 16);  // 2048 = 2 clean rounds of 256CU x 4

    init_state<<<(NB * NN + 255) / 256, 256, 0, stream>>>(satl, satr, costAcc);
    row_start<<<blocks, 256, 0, stream>>>(pred, gt, satl, satr, ratioL, c[0]);
    for (int j = 0; j <= 8; ++j) {
        col_pass<<<blocks, 256, 0, stream>>>(pred, gt, ratioL, ratioR, satr, c[j]);
        row_finish<0><<<blocks, 256, 0, stream>>>(pred, gt, satl, ratioL, ratioR, satr,
                                                  costAcc, c[j], c[j + 1]);
    }
    col_pass<<<blocks, 256, 0, stream>>>(pred, gt, ratioL, ratioR, satr, c[9]);
    row_finish<1><<<blocks, 256, 0, stream>>>(pred, gt, satl, ratioL, ratioR, satr,
                                              costAcc, c[9], 0.0f);
    col_last<<<NB, 256, 0, stream>>>(ratioL, ratioR, satr);
    row_finish<2><<<blocks, 256, 0, stream>>>(pred, gt, satl, ratioL, ratioR, satr,
                                              costAcc, 0.0f, 0.0f);
    finalize<<<1, 1, 0, stream>>>(costAcc, out);
}